// Round 2
// baseline (682.394 us; speedup 1.0000x reference)
//
#include <hip/hip_runtime.h>

typedef __attribute__((ext_vector_type(8))) short bf16x8;
typedef __attribute__((ext_vector_type(4))) float f32x4;
typedef unsigned short u16;
typedef unsigned int u32;

// dims
#define S_TOT 65536   // B*S = 16*4096
#define C_IN 512
#define N_CAT 384     // 64 theta + 64 phi + 256 g
#define G_CH 256

static __device__ __forceinline__ float b2f(u16 u) {
    u32 x = ((u32)u) << 16;
    return __builtin_bit_cast(float, x);
}
static __device__ __forceinline__ u16 f2b(float f) {
    u32 u = __builtin_bit_cast(u32, f);
    u32 r = (u + 0x7fffu + ((u >> 16) & 1u)) >> 16;
    return (u16)r;
}

// ---------------- weight packing (fp32 in): WcatT[384][512], WoT[512][256] bf16 ----------------
__global__ void pack_w(const float* __restrict__ Wt, const float* __restrict__ Wp,
                       const float* __restrict__ Wg, const float* __restrict__ Wo,
                       u16* __restrict__ WcatT, u16* __restrict__ WoT) {
    int t = blockIdx.x * 256 + threadIdx.x;
    const int n1 = N_CAT * C_IN; // 196608
    if (t < n1) {
        int n = t >> 9;      // row (output channel)
        int k = t & 511;     // col (input channel)
        float v;
        if (n < 64)       v = Wt[k * 64 + n];
        else if (n < 128) v = Wp[k * 64 + (n - 64)];
        else              v = Wg[k * 256 + (n - 128)];
        WcatT[t] = f2b(v);
    } else {
        int j = t - n1;
        if (j < 512 * 256) {
            int n = j >> 8;  // 0..511
            int k = j & 255;
            WoT[j] = f2b(Wo[k * 512 + n]);
        }
    }
}

// ---------------- 128x128 MFMA tile, A fp32 row-major [M][K], Bt bf16 row-major [N][K] ----------
template <int K>
static __device__ __forceinline__ void gemm_tile_f32A(const float* __restrict__ A,
                                                      const u16* __restrict__ Bt,
                                                      int m0, int n0, int lda, int ldb,
                                                      f32x4 acc[4][4], u16* As, u16* Bs) {
    const int t = threadIdx.x;
    const int lane = t & 63, w = t >> 6;
    const int li = lane & 15, quad = lane >> 4;
    const int wm = (w & 1) * 64, wn = (w >> 1) * 64;
#pragma unroll
    for (int mi = 0; mi < 4; mi++)
#pragma unroll
        for (int ni = 0; ni < 4; ni++) acc[mi][ni] = (f32x4)0.0f;
    const int r0 = t >> 2;          // 0..63
    const int ko = (t & 3) * 8;     // 0,8,16,24
    for (int k0 = 0; k0 < K; k0 += 32) {
#pragma unroll
        for (int i = 0; i < 2; i++) {
            int r = r0 + i * 64;
            const float* ap = A + (size_t)(m0 + r) * lda + k0 + ko;
            f32x4 f0 = *(const f32x4*)(ap);
            f32x4 f1 = *(const f32x4*)(ap + 4);
            bf16x8 v;
            v[0] = (short)f2b(f0[0]); v[1] = (short)f2b(f0[1]);
            v[2] = (short)f2b(f0[2]); v[3] = (short)f2b(f0[3]);
            v[4] = (short)f2b(f1[0]); v[5] = (short)f2b(f1[1]);
            v[6] = (short)f2b(f1[2]); v[7] = (short)f2b(f1[3]);
            *(bf16x8*)(As + r * 40 + ko) = v;
            *(bf16x8*)(Bs + r * 40 + ko) =
                *(const bf16x8*)(Bt + (size_t)(n0 + r) * ldb + k0 + ko);
        }
        __syncthreads();
        bf16x8 af[4], bfr[4];
#pragma unroll
        for (int mi = 0; mi < 4; mi++)
            af[mi] = *(const bf16x8*)(As + (wm + mi * 16 + li) * 40 + quad * 8);
#pragma unroll
        for (int ni = 0; ni < 4; ni++)
            bfr[ni] = *(const bf16x8*)(Bs + (wn + ni * 16 + li) * 40 + quad * 8);
#pragma unroll
        for (int mi = 0; mi < 4; mi++)
#pragma unroll
            for (int ni = 0; ni < 4; ni++)
                acc[mi][ni] = __builtin_amdgcn_mfma_f32_16x16x32_bf16(
                    af[mi], bfr[ni], acc[mi][ni], 0, 0, 0);
        __syncthreads();
    }
}

// ---------------- 128x128 MFMA tile, A bf16 [M][K], Bt bf16 [N][K] ----------
template <int K>
static __device__ __forceinline__ void gemm_tile_bf(const u16* __restrict__ A,
                                                    const u16* __restrict__ Bt,
                                                    int m0, int n0, int lda, int ldb,
                                                    f32x4 acc[4][4], u16* As, u16* Bs) {
    const int t = threadIdx.x;
    const int lane = t & 63, w = t >> 6;
    const int li = lane & 15, quad = lane >> 4;
    const int wm = (w & 1) * 64, wn = (w >> 1) * 64;
#pragma unroll
    for (int mi = 0; mi < 4; mi++)
#pragma unroll
        for (int ni = 0; ni < 4; ni++) acc[mi][ni] = (f32x4)0.0f;
    const int r0 = t >> 2;
    const int ko = (t & 3) * 8;
    for (int k0 = 0; k0 < K; k0 += 32) {
#pragma unroll
        for (int i = 0; i < 2; i++) {
            int r = r0 + i * 64;
            *(bf16x8*)(As + r * 40 + ko) =
                *(const bf16x8*)(A + (size_t)(m0 + r) * lda + k0 + ko);
            *(bf16x8*)(Bs + r * 40 + ko) =
                *(const bf16x8*)(Bt + (size_t)(n0 + r) * ldb + k0 + ko);
        }
        __syncthreads();
        bf16x8 af[4], bfr[4];
#pragma unroll
        for (int mi = 0; mi < 4; mi++)
            af[mi] = *(const bf16x8*)(As + (wm + mi * 16 + li) * 40 + quad * 8);
#pragma unroll
        for (int ni = 0; ni < 4; ni++)
            bfr[ni] = *(const bf16x8*)(Bs + (wn + ni * 16 + li) * 40 + quad * 8);
#pragma unroll
        for (int mi = 0; mi < 4; mi++)
#pragma unroll
            for (int ni = 0; ni < 4; ni++)
                acc[mi][ni] = __builtin_amdgcn_mfma_f32_16x16x32_bf16(
                    af[mi], bfr[ni], acc[mi][ni], 0, 0, 0);
        __syncthreads();
    }
}

// ---------------- proj: x[65536x512] fp32 @ Wcat -> theta [*,64] + ppg [*,320] (bf16) ----------
__global__ __launch_bounds__(256) void proj_gemm(const float* __restrict__ x,
                                                 const u16* __restrict__ WcatT,
                                                 u16* __restrict__ theta,
                                                 u16* __restrict__ ppg) {
    __shared__ __attribute__((aligned(16))) u16 As[128 * 40];
    __shared__ __attribute__((aligned(16))) u16 Bs[128 * 40];
    int bm = blockIdx.x / 3, bn = blockIdx.x % 3;
    f32x4 acc[4][4];
    gemm_tile_f32A<C_IN>(x, WcatT, bm * 128, bn * 128, C_IN, C_IN, acc, As, Bs);
    const int t = threadIdx.x;
    const int lane = t & 63, w = t >> 6, li = lane & 15, quad = lane >> 4;
    const int wm = (w & 1) * 64, wn = (w >> 1) * 64;
#pragma unroll
    for (int mi = 0; mi < 4; mi++)
#pragma unroll
        for (int ni = 0; ni < 4; ni++)
#pragma unroll
            for (int r = 0; r < 4; r++) {
                int row = bm * 128 + wm + mi * 16 + quad * 4 + r;
                int col = bn * 128 + wn + ni * 16 + li;
                u16 v = f2b(acc[mi][ni][r]);
                if (col < 64) theta[(size_t)row * 64 + col] = v;
                else          ppg[(size_t)row * 320 + (col - 64)] = v;
            }
}

// ---------------- maxpool phi: ppg cols 0..63 -> phi[b][1024][64] ----------------
__global__ void pool_phi(const u16* __restrict__ ppg, u16* __restrict__ phi) {
    int t = blockIdx.x * 256 + threadIdx.x; // 16*1024*64 total
    int c = t & 63;
    int pos = (t >> 6) & 1023;
    int b = t >> 16;
    int h2 = pos >> 5, w2 = pos & 31;
    size_t base = ((size_t)(b << 12) + h2 * 128 + w2 * 2) * 320 + c;
    float v0 = b2f(ppg[base]), v1 = b2f(ppg[base + 320]);
    float v2 = b2f(ppg[base + 320 * 64]), v3 = b2f(ppg[base + 320 * 65]);
    float m = fmaxf(fmaxf(v0, v1), fmaxf(v2, v3));
    phi[((size_t)(b << 10) + pos) * 64 + c] = f2b(m);
}

// ---------------- maxpool g, transposed out: gT[b][256][1024] ----------------
__global__ void pool_gt(const u16* __restrict__ ppg, u16* __restrict__ gT) {
    __shared__ float tile[64][65];
    int bid = blockIdx.x;
    int b = bid >> 6;
    int rem = bid & 63;
    int c0 = (rem >> 4) * 64;
    int pos0 = (rem & 15) * 64;
    int t = threadIdx.x;
#pragma unroll
    for (int i = 0; i < 16; i++) {
        int o = t + i * 256;
        int cl = o & 63, pl = o >> 6;
        int pos = pos0 + pl;
        int h2 = pos >> 5, w2 = pos & 31;
        size_t base = ((size_t)(b << 12) + h2 * 128 + w2 * 2) * 320 + 64 + c0 + cl;
        float v0 = b2f(ppg[base]), v1 = b2f(ppg[base + 320]);
        float v2 = b2f(ppg[base + 320 * 64]), v3 = b2f(ppg[base + 320 * 65]);
        tile[pl][cl] = fmaxf(fmaxf(v0, v1), fmaxf(v2, v3));
    }
    __syncthreads();
    int cl = t >> 2, ch = t & 3;
    u16 valbuf[16] __attribute__((aligned(16)));
#pragma unroll
    for (int j = 0; j < 16; j++) valbuf[j] = f2b(tile[ch * 16 + j][cl]);
    u16* dst = gT + ((size_t)b * 256 + c0 + cl) * 1024 + pos0 + ch * 16;
    *(uint4*)(dst) = *(const uint4*)(valbuf);
    *(uint4*)(dst + 8) = *(const uint4*)(valbuf + 8);
}

// ---------------- fused scores + softmax + PV (all bf16 internal) ----------------
__global__ __launch_bounds__(256) void attn_sv(const u16* __restrict__ theta,
                                               const u16* __restrict__ phi,
                                               const u16* __restrict__ gT,
                                               u16* __restrict__ tmp) {
    __shared__ __attribute__((aligned(16))) u16 betas[16 * 1032];
    __shared__ float red1[4][16];
    __shared__ float red2[4][16];
    int b = blockIdx.x >> 8;
    int q0 = (blockIdx.x & 255) * 16;
    int t = threadIdx.x;
    int w = t >> 6, lane = t & 63, li = lane & 15, quad = lane >> 4;

    const u16* thp = theta + ((size_t)b * 4096 + q0 + li) * 64 + quad * 8;
    bf16x8 a0 = *(const bf16x8*)(thp);
    bf16x8 a1 = *(const bf16x8*)(thp + 32);

    f32x4 sacc[16];
#pragma unroll
    for (int nf = 0; nf < 16; nf++) sacc[nf] = (f32x4)0.0f;
    const u16* php = phi + ((size_t)b * 1024 + w * 256 + li) * 64 + quad * 8;
#pragma unroll
    for (int nf = 0; nf < 16; nf++) {
        bf16x8 b0 = *(const bf16x8*)(php + (size_t)nf * 16 * 64);
        bf16x8 b1 = *(const bf16x8*)(php + (size_t)nf * 16 * 64 + 32);
        sacc[nf] = __builtin_amdgcn_mfma_f32_16x16x32_bf16(a0, b0, sacc[nf], 0, 0, 0);
        sacc[nf] = __builtin_amdgcn_mfma_f32_16x16x32_bf16(a1, b1, sacc[nf], 0, 0, 0);
    }

    float rmax[4];
#pragma unroll
    for (int r = 0; r < 4; r++) {
        float m = sacc[0][r];
#pragma unroll
        for (int nf = 1; nf < 16; nf++) m = fmaxf(m, sacc[nf][r]);
        for (int off = 1; off < 16; off <<= 1) m = fmaxf(m, __shfl_xor(m, off, 64));
        rmax[r] = m;
    }
    if (li == 0) {
#pragma unroll
        for (int r = 0; r < 4; r++) red1[w][quad * 4 + r] = rmax[r];
    }
    __syncthreads();
    float gmax[4];
#pragma unroll
    for (int r = 0; r < 4; r++) {
        int row = quad * 4 + r;
        gmax[r] = fmaxf(fmaxf(red1[0][row], red1[1][row]),
                        fmaxf(red1[2][row], red1[3][row]));
    }
    float rsum[4];
#pragma unroll
    for (int r = 0; r < 4; r++) {
        float s = 0.0f;
#pragma unroll
        for (int nf = 0; nf < 16; nf++) {
            float e = __expf(sacc[nf][r] - gmax[r]);
            sacc[nf][r] = e;
            s += e;
        }
        for (int off = 1; off < 16; off <<= 1) s += __shfl_xor(s, off, 64);
        rsum[r] = s;
    }
    if (li == 0) {
#pragma unroll
        for (int r = 0; r < 4; r++) red2[w][quad * 4 + r] = rsum[r];
    }
    __syncthreads();
    float inv[4];
#pragma unroll
    for (int r = 0; r < 4; r++) {
        int row = quad * 4 + r;
        inv[r] = 1.0f / (red2[0][row] + red2[1][row] + red2[2][row] + red2[3][row]);
    }
#pragma unroll
    for (int nf = 0; nf < 16; nf++)
#pragma unroll
        for (int r = 0; r < 4; r++)
            betas[(quad * 4 + r) * 1032 + w * 256 + nf * 16 + li] =
                f2b(sacc[nf][r] * inv[r]);
    __syncthreads();

    f32x4 o[4];
#pragma unroll
    for (int ni = 0; ni < 4; ni++) o[ni] = (f32x4)0.0f;
    const u16* gp = gT + ((size_t)b * 256 + w * 64 + li) * 1024 + quad * 8;
    for (int kk = 0; kk < 32; kk++) {
        bf16x8 afr = *(const bf16x8*)(betas + li * 1032 + kk * 32 + quad * 8);
#pragma unroll
        for (int ni = 0; ni < 4; ni++) {
            bf16x8 bfr = *(const bf16x8*)(gp + (size_t)ni * 16 * 1024 + kk * 32);
            o[ni] = __builtin_amdgcn_mfma_f32_16x16x32_bf16(afr, bfr, o[ni], 0, 0, 0);
        }
    }
#pragma unroll
    for (int ni = 0; ni < 4; ni++)
#pragma unroll
        for (int r = 0; r < 4; r++)
            tmp[((size_t)b * 4096 + q0 + quad * 4 + r) * 256 + w * 64 + ni * 16 + li] =
                f2b(o[ni][r]);
}

// ---------------- out: tmp[65536x256] bf16 @ W_o + gamma*o + x (fp32 out) ----------------
__global__ __launch_bounds__(256) void out_gemm(const u16* __restrict__ tmp,
                                                const u16* __restrict__ WoT,
                                                const float* __restrict__ x,
                                                const float* __restrict__ gamma_p,
                                                float* __restrict__ out) {
    __shared__ __attribute__((aligned(16))) u16 As[128 * 40];
    __shared__ __attribute__((aligned(16))) u16 Bs[128 * 40];
    int bm = blockIdx.x >> 2, bn = blockIdx.x & 3;
    f32x4 acc[4][4];
    gemm_tile_bf<G_CH>(tmp, WoT, bm * 128, bn * 128, G_CH, G_CH, acc, As, Bs);
    float gamma = gamma_p[0];
    const int t = threadIdx.x;
    const int lane = t & 63, w = t >> 6, li = lane & 15, quad = lane >> 4;
    const int wm = (w & 1) * 64, wn = (w >> 1) * 64;
#pragma unroll
    for (int mi = 0; mi < 4; mi++)
#pragma unroll
        for (int ni = 0; ni < 4; ni++)
#pragma unroll
            for (int r = 0; r < 4; r++) {
                int row = bm * 128 + wm + mi * 16 + quad * 4 + r;
                int col = bn * 128 + wn + ni * 16 + li;
                out[(size_t)row * 512 + col] =
                    gamma * acc[mi][ni][r] + x[(size_t)row * 512 + col];
            }
}

extern "C" void kernel_launch(void* const* d_in, const int* in_sizes, int n_in,
                              void* d_out, int out_size, void* d_ws, size_t ws_size,
                              hipStream_t stream) {
    (void)in_sizes; (void)n_in; (void)out_size; (void)ws_size;
    const float* x  = (const float*)d_in[0];
    const float* Wt = (const float*)d_in[1];
    const float* Wp = (const float*)d_in[2];
    const float* Wg = (const float*)d_in[3];
    const float* Wo = (const float*)d_in[4];
    const float* gm = (const float*)d_in[5];
    float* out = (float*)d_out;

    char* ws = (char*)d_ws;
    size_t off = 0;
    u16* WcatT = (u16*)(ws + off); off += (size_t)384 * 512 * 2;
    u16* WoT   = (u16*)(ws + off); off += (size_t)512 * 256 * 2;
    u16* theta = (u16*)(ws + off); off += (size_t)S_TOT * 64 * 2;
    u16* ppg   = (u16*)(ws + off); off += (size_t)S_TOT * 320 * 2;
    u16* phi   = (u16*)(ws + off); off += (size_t)16 * 1024 * 64 * 2;
    u16* gT    = (u16*)(ws + off); off += (size_t)16 * 256 * 1024 * 2;
    u16* tmp   = ppg;  // alias: ppg is dead after pool_phi/pool_gt
    // total ws usage: ~58.6 MiB

    pack_w<<<1280, 256, 0, stream>>>(Wt, Wp, Wg, Wo, WcatT, WoT);
    proj_gemm<<<1536, 256, 0, stream>>>(x, WcatT, theta, ppg);
    pool_phi<<<4096, 256, 0, stream>>>(ppg, phi);
    pool_gt<<<1024, 256, 0, stream>>>(ppg, gT);
    attn_sv<<<4096, 256, 0, stream>>>(theta, phi, gT, tmp);
    out_gemm<<<2048, 256, 0, stream>>>(tmp, WoT, x, gm, out);
}

// Round 3
// 508.548 us; speedup vs baseline: 1.3418x; 1.3418x over previous
//
#include <hip/hip_runtime.h>

typedef __attribute__((ext_vector_type(8))) short bf16x8;
typedef __attribute__((ext_vector_type(4))) float f32x4;
typedef unsigned short u16;
typedef unsigned int u32;

#define MFMA __builtin_amdgcn_mfma_f32_16x16x32_bf16

static __device__ __forceinline__ float b2f(u16 u) {
    u32 x = ((u32)u) << 16;
    return __builtin_bit_cast(float, x);
}
static __device__ __forceinline__ u16 f2b(float f) {
    u32 u = __builtin_bit_cast(u32, f);
    u32 r = (u + 0x7fffu + ((u >> 16) & 1u)) >> 16;
    return (u16)r;
}
// async 16B/lane global->LDS DMA; lds base must be wave-uniform, lane i lands at +i*16
static __device__ __forceinline__ void async16(const u16* g, u16* l) {
    __builtin_amdgcn_global_load_lds(
        (const __attribute__((address_space(1))) u32*)g,
        (__attribute__((address_space(3))) u32*)l, 16, 0, 0);
}

// ---------------- x fp32 -> bf16 ----------------
__global__ __launch_bounds__(256) void xcast(const float* __restrict__ x, u16* __restrict__ xb) {
    size_t i = ((size_t)blockIdx.x * 256 + threadIdx.x) * 8;
    f32x4 f0 = *(const f32x4*)(x + i);
    f32x4 f1 = *(const f32x4*)(x + i + 4);
    bf16x8 v;
    v[0] = (short)f2b(f0[0]); v[1] = (short)f2b(f0[1]);
    v[2] = (short)f2b(f0[2]); v[3] = (short)f2b(f0[3]);
    v[4] = (short)f2b(f1[0]); v[5] = (short)f2b(f1[1]);
    v[6] = (short)f2b(f1[2]); v[7] = (short)f2b(f1[3]);
    *(bf16x8*)(xb + i) = v;
}

// ---------------- weight packing: WcatT[384][512], WoT[512][256] ----------------
__global__ void pack_w(const float* __restrict__ Wt, const float* __restrict__ Wp,
                       const float* __restrict__ Wg, const float* __restrict__ Wo,
                       u16* __restrict__ WcatT, u16* __restrict__ WoT) {
    int t = blockIdx.x * 256 + threadIdx.x;
    const int n1 = 384 * 512;
    if (t < n1) {
        int n = t >> 9, k = t & 511;
        float v;
        if (n < 64)       v = Wt[k * 64 + n];
        else if (n < 128) v = Wp[k * 64 + (n - 64)];
        else              v = Wg[k * 256 + (n - 128)];
        WcatT[t] = f2b(v);
    } else {
        int j = t - n1;
        if (j < 512 * 256) {
            int n = j >> 8, k = j & 255;
            WoT[j] = f2b(Wo[k * 512 + n]);
        }
    }
}

// ---------------- m97-style 128x128 GEMM core: A[M][K] bf16, Bt[N][K] bf16 ----------------
template <int K>
static __device__ __forceinline__ void gemm_core(const u16* __restrict__ A,
                                                 const u16* __restrict__ Bt,
                                                 int m0, int n0, int lda, int ldb,
                                                 f32x4 acc[4][4], u16* As, u16* Bs) {
    const int t = threadIdx.x;
    const int w = t >> 6, li = t & 15, quad = (t >> 4) & 3;
    const int wm = (w & 1) << 6, wn = (w >> 1) << 6;
#pragma unroll
    for (int mi = 0; mi < 4; mi++)
#pragma unroll
        for (int ni = 0; ni < 4; ni++) acc[mi][ni] = (f32x4)0.0f;
    const u16* ag = A + (size_t)(m0 + (t >> 2)) * lda + ((t & 3) << 3);
    const u16* bg = Bt + (size_t)(n0 + (t >> 2)) * ldb + ((t & 3) << 3);
    u16* asw = As + w * 512;
    u16* bsw = Bs + w * 512;
    for (int k0 = 0; k0 < K; k0 += 32) {
        __syncthreads();
        async16(ag + k0, asw);
        async16(ag + k0 + (size_t)64 * lda, asw + 2048);
        async16(bg + k0, bsw);
        async16(bg + k0 + (size_t)64 * ldb, bsw + 2048);
        __syncthreads();
        bf16x8 af[4], bfr[4];
#pragma unroll
        for (int mi = 0; mi < 4; mi++)
            af[mi] = *(const bf16x8*)(As + (wm + mi * 16 + li) * 32 + quad * 8);
#pragma unroll
        for (int ni = 0; ni < 4; ni++)
            bfr[ni] = *(const bf16x8*)(Bs + (wn + ni * 16 + li) * 32 + quad * 8);
#pragma unroll
        for (int mi = 0; mi < 4; mi++)
#pragma unroll
            for (int ni = 0; ni < 4; ni++)
                acc[mi][ni] = MFMA(af[mi], bfr[ni], acc[mi][ni], 0, 0, 0);
    }
    __syncthreads();  // allow epilogue to reuse As/Bs LDS
}

// per-wave LDS transpose epilogue -> coalesced 16B bf16 stores (64x64 quadrant)
static __device__ __forceinline__ void epi_bf16(const f32x4 acc[4][4], u16* ebuf,
                                                u16* __restrict__ outp, int ld,
                                                int row0, int col0) {
    const int t = threadIdx.x;
    const int li = t & 15, quad = (t >> 4) & 3;
#pragma unroll
    for (int mi = 0; mi < 4; mi++)
#pragma unroll
        for (int ni = 0; ni < 4; ni++)
#pragma unroll
            for (int r = 0; r < 4; r++)
                ebuf[(mi * 16 + quad * 4 + r) * 72 + ni * 16 + li] = f2b(acc[mi][ni][r]);
    const int rr = (t & 63) >> 3, cc = (t & 7) * 8;
#pragma unroll
    for (int j = 0; j < 8; j++) {
        int row = j * 8 + rr;
        bf16x8 v = *(const bf16x8*)(ebuf + row * 72 + cc);
        *(bf16x8*)(outp + (size_t)(row0 + row) * ld + col0 + cc) = v;
    }
}

// ---------------- proj: xb[65536x512] @ WcatT -> theta[*,64] + ppg[*,320] ----------------
__global__ __launch_bounds__(256) void proj_gemm(const u16* __restrict__ xb,
                                                 const u16* __restrict__ WcatT,
                                                 u16* __restrict__ theta,
                                                 u16* __restrict__ ppg) {
    __shared__ __attribute__((aligned(16))) u16 sbuf[18432];  // 36 KB
    u16* As = sbuf;
    u16* Bs = sbuf + 4096;
    int bm = blockIdx.x / 3, bn = blockIdx.x % 3;
    f32x4 acc[4][4];
    gemm_core<512>(xb, WcatT, bm * 128, bn * 128, 512, 512, acc, As, Bs);
    const int w = threadIdx.x >> 6;
    u16* ebuf = sbuf + w * 4608;
    int row0 = bm * 128 + (w & 1) * 64;
    int gcol = bn * 128 + (w >> 1) * 64;
    if (gcol < 64) epi_bf16(acc, ebuf, theta, 64, row0, 0);
    else           epi_bf16(acc, ebuf, ppg, 320, row0, gcol - 64);
}

// ---------------- maxpool phi: ppg cols 0..63 -> phi[b][1024][64] ----------------
__global__ void pool_phi(const u16* __restrict__ ppg, u16* __restrict__ phi) {
    int t = blockIdx.x * 256 + threadIdx.x;
    int c = t & 63;
    int pos = (t >> 6) & 1023;
    int b = t >> 16;
    int h2 = pos >> 5, w2 = pos & 31;
    size_t base = ((size_t)(b << 12) + h2 * 128 + w2 * 2) * 320 + c;
    float v0 = b2f(ppg[base]), v1 = b2f(ppg[base + 320]);
    float v2 = b2f(ppg[base + 320 * 64]), v3 = b2f(ppg[base + 320 * 65]);
    float m = fmaxf(fmaxf(v0, v1), fmaxf(v2, v3));
    phi[((size_t)(b << 10) + pos) * 64 + c] = f2b(m);
}

// ---------------- maxpool g, transposed: gT[b][256][1024] ----------------
__global__ void pool_gt(const u16* __restrict__ ppg, u16* __restrict__ gT) {
    __shared__ float tile[64][65];
    int bid = blockIdx.x;
    int b = bid >> 6;
    int rem = bid & 63;
    int c0 = (rem >> 4) * 64;
    int pos0 = (rem & 15) * 64;
    int t = threadIdx.x;
#pragma unroll
    for (int i = 0; i < 16; i++) {
        int o = t + i * 256;
        int cl = o & 63, pl = o >> 6;
        int pos = pos0 + pl;
        int h2 = pos >> 5, w2 = pos & 31;
        size_t base = ((size_t)(b << 12) + h2 * 128 + w2 * 2) * 320 + 64 + c0 + cl;
        float v0 = b2f(ppg[base]), v1 = b2f(ppg[base + 320]);
        float v2 = b2f(ppg[base + 320 * 64]), v3 = b2f(ppg[base + 320 * 65]);
        tile[pl][cl] = fmaxf(fmaxf(v0, v1), fmaxf(v2, v3));
    }
    __syncthreads();
    int cl = t >> 2, ch = t & 3;
    u16 valbuf[16] __attribute__((aligned(16)));
#pragma unroll
    for (int j = 0; j < 16; j++) valbuf[j] = f2b(tile[ch * 16 + j][cl]);
    u16* dst = gT + ((size_t)b * 256 + c0 + cl) * 1024 + pos0 + ch * 16;
    *(uint4*)(dst) = *(const uint4*)(valbuf);
    *(uint4*)(dst + 8) = *(const uint4*)(valbuf + 8);
}

// ---------------- fused scores + softmax + PV, DMA-staged through 64 KB LDS ----------------
__global__ __launch_bounds__(256) void attn_fused(const u16* __restrict__ theta,
                                                  const u16* __restrict__ phi,
                                                  const u16* __restrict__ gT,
                                                  u16* __restrict__ tmp) {
    __shared__ __attribute__((aligned(16))) u16 lds[32768];  // 64 KB
    u16* stg = lds;            // 32 KB staging (phi tiles, then gT tiles, then epilogue)
    u16* bet = lds + 16384;    // 32 KB betas [16][1024], xor-swizzled chunks
    float* red = (float*)lds;  // red1=[0:64) red2=[64:128), overlays stg rows 0-3 (wave-0 only)

    int b = blockIdx.x >> 8;
    int q0 = (blockIdx.x & 255) << 4;
    const int t = threadIdx.x;
    const int w = t >> 6, li = t & 15, quad = (t >> 4) & 3;

    // theta A-frags (rows q0+li, k = quad*8 + [0,32))
    const u16* thp = theta + (((size_t)(b << 12) + q0 + li) << 6) + quad * 8;
    bf16x8 a0 = *(const bf16x8*)thp;
    bf16x8 a1 = *(const bf16x8*)(thp + 32);

    // DMA source swizzle: LDS chunk position p=j*256+t -> row=j*32+(t>>3), pos=t&7,
    // global chunk c = pos ^ (row&7) = (t&7) ^ ((t>>3)&7)
    const int srow = t >> 3;
    const int sc = (t & 7) ^ (srow & 7);
    const u16* phisrc = phi + ((size_t)(b << 10) + srow) * 64 + sc * 8;
    const u16* gsrc = gT + ((size_t)(b << 8) + srow) * 1024 + sc * 8;

    // ---- scores: 4 passes of 256 keys ----
    f32x4 sacc[16];
#pragma unroll
    for (int nf = 0; nf < 16; nf++) sacc[nf] = (f32x4)0.0f;
    for (int pass = 0; pass < 4; pass++) {
        __syncthreads();
#pragma unroll
        for (int j = 0; j < 8; j++)
            async16(phisrc + (size_t)(pass * 256 + j * 32) * 64, stg + j * 2048 + w * 512);
        __syncthreads();
#pragma unroll
        for (int f = 0; f < 4; f++) {
            int rt = w * 64 + f * 16 + li;          // staged row; rt&7 == li&7
            int p0 = quad ^ (li & 7);
            int p1 = (quad + 4) ^ (li & 7);
            bf16x8 b0 = *(const bf16x8*)(stg + rt * 64 + p0 * 8);
            bf16x8 b1 = *(const bf16x8*)(stg + rt * 64 + p1 * 8);
            sacc[pass * 4 + f] = MFMA(a0, b0, sacc[pass * 4 + f], 0, 0, 0);
            sacc[pass * 4 + f] = MFMA(a1, b1, sacc[pass * 4 + f], 0, 0, 0);
        }
    }

    // ---- softmax over 1024 keys (rows = quad*4+r) ----
    float rmax[4];
#pragma unroll
    for (int r = 0; r < 4; r++) {
        float m = sacc[0][r];
#pragma unroll
        for (int nf = 1; nf < 16; nf++) m = fmaxf(m, sacc[nf][r]);
        for (int off = 1; off < 16; off <<= 1) m = fmaxf(m, __shfl_xor(m, off, 64));
        rmax[r] = m;
    }
    __syncthreads();
    if (li == 0) {
#pragma unroll
        for (int r = 0; r < 4; r++) red[w * 16 + quad * 4 + r] = rmax[r];
    }
    __syncthreads();
    float gmax[4];
#pragma unroll
    for (int r = 0; r < 4; r++) {
        int row = quad * 4 + r;
        gmax[r] = fmaxf(fmaxf(red[row], red[16 + row]), fmaxf(red[32 + row], red[48 + row]));
    }
    float rsum[4];
#pragma unroll
    for (int r = 0; r < 4; r++) {
        float s = 0.0f;
#pragma unroll
        for (int nf = 0; nf < 16; nf++) {
            float e = __expf(sacc[nf][r] - gmax[r]);
            sacc[nf][r] = e;
            s += e;
        }
        for (int off = 1; off < 16; off <<= 1) s += __shfl_xor(s, off, 64);
        rsum[r] = s;
    }
    if (li == 0) {
#pragma unroll
        for (int r = 0; r < 4; r++) red[64 + w * 16 + quad * 4 + r] = rsum[r];
    }
    __syncthreads();
    float inv[4];
#pragma unroll
    for (int r = 0; r < 4; r++) {
        int row = quad * 4 + r;
        inv[r] = 1.0f / (red[64 + row] + red[80 + row] + red[96 + row] + red[112 + row]);
    }

    // ---- betas -> LDS, xor-swizzled within 8-chunk groups ----
#pragma unroll
    for (int p = 0; p < 4; p++)
#pragma unroll
        for (int f = 0; f < 4; f++)
#pragma unroll
            for (int r = 0; r < 4; r++) {
                int row = quad * 4 + r;
                int col = p * 256 + w * 64 + f * 16 + li;
                int ch = col >> 3, e = col & 7;
                int pos = ch ^ (row & 7);
                bet[row * 1024 + pos * 8 + e] = f2b(sacc[p * 4 + f][r] * inv[r]);
            }
    __syncthreads();

    // ---- PV: 16 chunks of 64 k, gT staged through stg; wave w owns v-cols [w*64, w*64+64) ----
    f32x4 o[4];
#pragma unroll
    for (int ni = 0; ni < 4; ni++) o[ni] = (f32x4)0.0f;
    for (int kc = 0; kc < 16; kc++) {
        __syncthreads();
#pragma unroll
        for (int j = 0; j < 8; j++)
            async16(gsrc + (size_t)(j * 32) * 1024 + kc * 64, stg + j * 2048 + w * 512);
        __syncthreads();
#pragma unroll
        for (int kk = 0; kk < 2; kk++) {
            int ach = kc * 8 + kk * 4 + quad;
            int apos = ach ^ (li & 7);
            bf16x8 afr = *(const bf16x8*)(bet + li * 1024 + apos * 8);
#pragma unroll
            for (int ni = 0; ni < 4; ni++) {
                int vr = w * 64 + ni * 16 + li;     // vr&7 == li&7
                int bpos = (kk * 4 + quad) ^ (li & 7);
                bf16x8 bfr = *(const bf16x8*)(stg + vr * 64 + bpos * 8);
                o[ni] = MFMA(afr, bfr, o[ni], 0, 0, 0);
            }
        }
    }

    // ---- epilogue: per-wave transpose -> coalesced 16B stores ----
    __syncthreads();
    u16* eb = stg + w * 1152;  // 16 x 72
#pragma unroll
    for (int ni = 0; ni < 4; ni++)
#pragma unroll
        for (int r = 0; r < 4; r++)
            eb[(quad * 4 + r) * 72 + ni * 16 + li] = f2b(o[ni][r]);
    const int rr = (t & 63) >> 2, cc4 = t & 3;
#pragma unroll
    for (int j = 0; j < 2; j++) {
        bf16x8 v = *(const bf16x8*)(eb + rr * 72 + cc4 * 8 + j * 32);
        *(bf16x8*)(tmp + ((size_t)(b << 12) + q0 + rr) * 256 + w * 64 + cc4 * 8 + j * 32) = v;
    }
}

// ---------------- out: tmp[65536x256] @ WoT + gamma*o + x (fp32) ----------------
__global__ __launch_bounds__(256) void out_gemm(const u16* __restrict__ tmp,
                                                const u16* __restrict__ WoT,
                                                const float* __restrict__ x,
                                                const float* __restrict__ gamma_p,
                                                float* __restrict__ out) {
    __shared__ __attribute__((aligned(16))) u16 sbuf[18432];
    u16* As = sbuf;
    u16* Bs = sbuf + 4096;
    int bm = blockIdx.x >> 2, bn = blockIdx.x & 3;
    f32x4 acc[4][4];
    gemm_core<256>(tmp, WoT, bm * 128, bn * 128, 256, 256, acc, As, Bs);
    float gamma = gamma_p[0];
    const int t = threadIdx.x;
    const int w = t >> 6, li = t & 15, quad = (t >> 4) & 3;
    int row0 = bm * 128 + (w & 1) * 64;
    int col0 = bn * 128 + (w >> 1) * 64;
    float* fb = (float*)sbuf + w * 2176;  // 32 x 68 fp32 per wave
    const int rr = (t & 63) >> 4, ccv = (t & 15) * 4;
#pragma unroll
    for (int half = 0; half < 2; half++) {
#pragma unroll
        for (int mi = 0; mi < 2; mi++)
#pragma unroll
            for (int ni = 0; ni < 4; ni++)
#pragma unroll
                for (int r = 0; r < 4; r++)
                    fb[(mi * 16 + quad * 4 + r) * 68 + ni * 16 + li] =
                        acc[half * 2 + mi][ni][r];
#pragma unroll
        for (int j = 0; j < 8; j++) {
            int row = j * 4 + rr;
            f32x4 v = *(const f32x4*)(fb + row * 68 + ccv);
            size_t go = (size_t)(row0 + half * 32 + row) * 512 + col0 + ccv;
            f32x4 xv = *(const f32x4*)(x + go);
#pragma unroll
            for (int e = 0; e < 4; e++) v[e] = gamma * v[e] + xv[e];
            *(f32x4*)(out + go) = v;
        }
    }
}

extern "C" void kernel_launch(void* const* d_in, const int* in_sizes, int n_in,
                              void* d_out, int out_size, void* d_ws, size_t ws_size,
                              hipStream_t stream) {
    (void)in_sizes; (void)n_in; (void)out_size; (void)ws_size;
    const float* x  = (const float*)d_in[0];
    const float* Wt = (const float*)d_in[1];
    const float* Wp = (const float*)d_in[2];
    const float* Wg = (const float*)d_in[3];
    const float* Wo = (const float*)d_in[4];
    const float* gm = (const float*)d_in[5];
    float* out = (float*)d_out;

    char* ws = (char*)d_ws;
    size_t off = 0;
    u16* WcatT = (u16*)(ws + off); off += (size_t)384 * 512 * 2;
    u16* WoT   = (u16*)(ws + off); off += (size_t)512 * 256 * 2;
    u16* xb    = (u16*)(ws + off); off += (size_t)65536 * 512 * 2;   // 64 MiB
    u16* theta = (u16*)(ws + off); off += (size_t)65536 * 64 * 2;    // 8 MiB
    u16* ppg   = (u16*)(ws + off); off += (size_t)65536 * 320 * 2;   // 40 MiB
    // aliases: xb dead after proj -> phi/gT live there; ppg dead after pools -> tmp
    u16* phi = xb;                                   // 2 MiB
    u16* gT  = xb + (size_t)16 * 1024 * 64;          // 8 MiB
    u16* tmp = ppg;                                  // 32 MiB
    // total ws: ~112.6 MiB

    pack_w<<<1280, 256, 0, stream>>>(Wt, Wp, Wg, Wo, WcatT, WoT);
    xcast<<<16384, 256, 0, stream>>>(x, xb);
    proj_gemm<<<1536, 256, 0, stream>>>(xb, WcatT, theta, ppg);
    pool_phi<<<4096, 256, 0, stream>>>(ppg, phi);
    pool_gt<<<1024, 256, 0, stream>>>(ppg, gT);
    attn_fused<<<4096, 256, 0, stream>>>(theta, phi, gT, tmp);
    out_gemm<<<2048, 256, 0, stream>>>(tmp, WoT, x, gm, out);
}